// Round 1
// baseline (1701.842 us; speedup 1.0000x reference)
//
#include <hip/hip_runtime.h>

// CTRNN: T=512 steps, B=256 batch, I=64 input, H=256 hidden.
// pre = x_t @ W_in^T + b_in + h @ W_hh^T + b_hh + noise_t
// h   = max(0.8*h + 0.2*pre, 0)
//
// Decomposition: batch elements evolve independently -> one persistent block
// per batch element (256 blocks = 1/CU), no grid sync ever. Thread j owns
// hidden unit j; W_hh[j,:] (256 f32) and W_in[j,:] (64 f32) live in VGPRs
// (~390 regs, 1 wave/SIMD via __launch_bounds__(256,1)). h is double-buffered
// in LDS; all lanes read the same address per chunk -> LDS broadcast, no
// bank conflicts. One __syncthreads per step.

#define T_STEPS 512
#define BATCH   256
#define INSZ    64
#define HID     256
#define ALPHA_F 0.2f
#define OMA_F   0.8f

__global__ __launch_bounds__(256, 1)
void ctrnn_kernel(const float* __restrict__ x,       // [T, B, I]
                  const float* __restrict__ hidden,  // [B, H]
                  const float* __restrict__ noise,   // [T, H]
                  const float* __restrict__ W_in,    // [H, I]
                  const float* __restrict__ b_in,    // [H]
                  const float* __restrict__ W_hh,    // [H, H]
                  const float* __restrict__ b_hh,    // [H]
                  float* __restrict__ out)           // [T,B,H] ++ [B,H]
{
    const int b = blockIdx.x;   // batch element
    const int j = threadIdx.x;  // hidden unit

    __shared__ __align__(16) float hbuf[2][HID];
    __shared__ __align__(16) float xbuf[2][INSZ];

    // --- Load weight rows into registers (one-time; L2-served after first blocks) ---
    float whh[HID];
#pragma unroll
    for (int k = 0; k < HID; k += 4) {
        float4 v = *reinterpret_cast<const float4*>(&W_hh[j * HID + k]);
        whh[k]   = v.x; whh[k+1] = v.y; whh[k+2] = v.z; whh[k+3] = v.w;
    }
    float win[INSZ];
#pragma unroll
    for (int k = 0; k < INSZ; k += 4) {
        float4 v = *reinterpret_cast<const float4*>(&W_in[j * INSZ + k]);
        win[k]   = v.x; win[k+1] = v.y; win[k+2] = v.z; win[k+3] = v.w;
    }
    const float bias = b_in[j] + b_hh[j];

    // --- Initial state + step-0 inputs ---
    float hj = hidden[b * HID + j];
    hbuf[0][j] = hj;
    if (j < INSZ / 4) {
        *reinterpret_cast<float4*>(&xbuf[0][4 * j]) =
            *reinterpret_cast<const float4*>(&x[(size_t)b * INSZ + 4 * j]);
    }
    float noise_j = noise[j];
    __syncthreads();

    int cur = 0;
#pragma unroll 1
    for (int t = 0; t < T_STEPS; ++t) {
        // Prefetch next step's x tile and noise while we compute this step.
        float4 xnext = make_float4(0.f, 0.f, 0.f, 0.f);
        float  nnext = 0.f;
        if (t + 1 < T_STEPS) {
            if (j < INSZ / 4) {
                xnext = *reinterpret_cast<const float4*>(
                    &x[((size_t)(t + 1) * BATCH + b) * INSZ + 4 * j]);
            }
            nnext = noise[(t + 1) * HID + j];
        }

        // pre_j = sum_k W_hh[j,k]*h[k] + sum_i W_in[j,i]*x_t[i]
        float acc0 = 0.f, acc1 = 0.f, acc2 = 0.f, acc3 = 0.f;
#pragma unroll
        for (int k = 0; k < HID; k += 4) {
            float4 hv = *reinterpret_cast<const float4*>(&hbuf[cur][k]);
            acc0 = fmaf(whh[k],     hv.x, acc0);
            acc1 = fmaf(whh[k + 1], hv.y, acc1);
            acc2 = fmaf(whh[k + 2], hv.z, acc2);
            acc3 = fmaf(whh[k + 3], hv.w, acc3);
        }
#pragma unroll
        for (int k = 0; k < INSZ; k += 4) {
            float4 xv = *reinterpret_cast<const float4*>(&xbuf[cur][k]);
            acc0 = fmaf(win[k],     xv.x, acc0);
            acc1 = fmaf(win[k + 1], xv.y, acc1);
            acc2 = fmaf(win[k + 2], xv.z, acc2);
            acc3 = fmaf(win[k + 3], xv.w, acc3);
        }
        const float pre = ((acc0 + acc1) + (acc2 + acc3)) + bias + noise_j;
        hj = fmaxf(fmaf(OMA_F, hj, ALPHA_F * pre), 0.f);

        // Stream the per-step output (coalesced 1 KB per block per step).
        out[((size_t)t * BATCH + b) * HID + j] = hj;

        // Publish state for next step into the other buffer; single barrier.
        const int nxt = cur ^ 1;
        hbuf[nxt][j] = hj;
        if (j < INSZ / 4) {
            *reinterpret_cast<float4*>(&xbuf[nxt][4 * j]) = xnext;
        }
        noise_j = nnext;
        __syncthreads();
        cur = nxt;
    }

    // h_last, concatenated after out: offset T*B*H.
    out[(size_t)T_STEPS * BATCH * HID + (size_t)b * HID + j] = hj;
}

extern "C" void kernel_launch(void* const* d_in, const int* in_sizes, int n_in,
                              void* d_out, int out_size, void* d_ws, size_t ws_size,
                              hipStream_t stream) {
    const float* x      = (const float*)d_in[0];
    const float* hidden = (const float*)d_in[1];
    const float* noise  = (const float*)d_in[2];
    const float* W_in   = (const float*)d_in[3];
    const float* b_in   = (const float*)d_in[4];
    const float* W_hh   = (const float*)d_in[5];
    const float* b_hh   = (const float*)d_in[6];
    float* out = (float*)d_out;

    hipLaunchKernelGGL(ctrnn_kernel, dim3(BATCH), dim3(HID), 0, stream,
                       x, hidden, noise, W_in, b_in, W_hh, b_hh, out);
}

// Round 2
// 632.331 us; speedup vs baseline: 2.6914x; 2.6914x over previous
//
#include <hip/hip_runtime.h>

// CTRNN: T=512, B=256, I=64, H=256.
//   pre = x_t @ W_in^T + b_in + h @ W_hh^T + b_hh + noise_t
//   h   = max(0.8*h + 0.2*pre, 0)
//
// R1 lesson: 256 threads/row needed 320 weight regs -> compiler kept only 176
// VGPRs and re-streamed weights from L2 every step (~1.24 ms L2-bound, matched
// observed 1.62 ms). Fix: 2-way k-split. 512 threads/block; thread (half, j)
// holds W_hh[j, half*128 .. +128) and W_in[j, half*32 .. +32) in registers
// (~200 VGPRs < 256 => 2 waves/SIMD). half=1 writes partial dot to LDS,
// half=0 combines, updates h, streams output. h/x double-buffered in LDS,
// all lanes read uniform addresses (broadcast, conflict-free).

#define T_STEPS 512
#define BATCH   256
#define INSZ    64
#define HID     256
#define KH      128   // per-thread W_hh chunk
#define KI      32    // per-thread W_in chunk
#define ALPHA_F 0.2f
#define OMA_F   0.8f

__global__ __launch_bounds__(512, 2)
void ctrnn_kernel(const float* __restrict__ x,       // [T, B, I]
                  const float* __restrict__ hidden,  // [B, H]
                  const float* __restrict__ noise,   // [T, H]
                  const float* __restrict__ W_in,    // [H, I]
                  const float* __restrict__ b_in,    // [H]
                  const float* __restrict__ W_hh,    // [H, H]
                  const float* __restrict__ b_hh,    // [H]
                  float* __restrict__ out)           // [T,B,H] ++ [B,H]
{
    const int tid  = threadIdx.x;
    const int j    = tid & (HID - 1);   // hidden unit (row)
    const int half = tid >> 8;          // k-chunk; wave-uniform (waves 0-3 vs 4-7)
    const int b    = blockIdx.x;

    __shared__ __align__(16) float hbuf[2][HID];
    __shared__ __align__(16) float xbuf[2][INSZ];
    __shared__ __align__(16) float pbuf[HID];

    // ---- Resident weights: 128 + 32 floats per thread ----
    float whh[KH];
    const float* wrow = &W_hh[j * HID + half * KH];
#pragma unroll
    for (int k = 0; k < KH; k += 4) {
        float4 v = *reinterpret_cast<const float4*>(&wrow[k]);
        whh[k] = v.x; whh[k+1] = v.y; whh[k+2] = v.z; whh[k+3] = v.w;
    }
    float win[KI];
    const float* wirow = &W_in[j * INSZ + half * KI];
#pragma unroll
    for (int k = 0; k < KI; k += 4) {
        float4 v = *reinterpret_cast<const float4*>(&wirow[k]);
        win[k] = v.x; win[k+1] = v.y; win[k+2] = v.z; win[k+3] = v.w;
    }

    float bias = 0.f, hj = 0.f, noise_j = 0.f;
    if (half == 0) {
        bias = b_in[j] + b_hh[j];
        hj = hidden[b * HID + j];
        hbuf[0][j] = hj;
        noise_j = noise[j];
        if (j < INSZ / 4) {
            *reinterpret_cast<float4*>(&xbuf[0][4 * j]) =
                *reinterpret_cast<const float4*>(&x[(size_t)b * INSZ + 4 * j]);
        }
    }
    __syncthreads();

    const int hoff = half * KH;
    const int ioff = half * KI;

    int cur = 0;
#pragma unroll 1
    for (int t = 0; t < T_STEPS; ++t) {
        // Prefetch next step's inputs while computing this step.
        float4 xnext = make_float4(0.f, 0.f, 0.f, 0.f);
        float  nnext = 0.f;
        if (half == 1) {
            if (j < INSZ / 4 && t + 1 < T_STEPS) {
                xnext = *reinterpret_cast<const float4*>(
                    &x[((size_t)(t + 1) * BATCH + b) * INSZ + 4 * j]);
            }
        } else if (t + 1 < T_STEPS) {
            nnext = noise[(t + 1) * HID + j];
        }

        // Partial dot over this thread's k-chunk (LDS broadcast reads).
        float acc0 = 0.f, acc1 = 0.f, acc2 = 0.f, acc3 = 0.f;
#pragma unroll
        for (int k = 0; k < KH; k += 4) {
            float4 hv = *reinterpret_cast<const float4*>(&hbuf[cur][hoff + k]);
            acc0 = fmaf(whh[k],     hv.x, acc0);
            acc1 = fmaf(whh[k + 1], hv.y, acc1);
            acc2 = fmaf(whh[k + 2], hv.z, acc2);
            acc3 = fmaf(whh[k + 3], hv.w, acc3);
        }
#pragma unroll
        for (int k = 0; k < KI; k += 4) {
            float4 xv = *reinterpret_cast<const float4*>(&xbuf[cur][ioff + k]);
            acc0 = fmaf(win[k],     xv.x, acc0);
            acc1 = fmaf(win[k + 1], xv.y, acc1);
            acc2 = fmaf(win[k + 2], xv.z, acc2);
            acc3 = fmaf(win[k + 3], xv.w, acc3);
        }
        const float acc = (acc0 + acc1) + (acc2 + acc3);

        if (half == 1) pbuf[j] = acc;
        __syncthreads();   // pbuf visible; hbuf[cur] reads done (dbuf => only pbuf matters)

        const int nxt = cur ^ 1;
        if (half == 0) {
            const float pre = acc + pbuf[j] + bias + noise_j;
            hj = fmaxf(fmaf(OMA_F, hj, ALPHA_F * pre), 0.f);
            out[((size_t)t * BATCH + b) * HID + j] = hj;   // coalesced 1 KB/step
            hbuf[nxt][j] = hj;
            noise_j = nnext;
        } else if (j < INSZ / 4 && t + 1 < T_STEPS) {
            *reinterpret_cast<float4*>(&xbuf[nxt][4 * j]) = xnext;
        }
        __syncthreads();   // hbuf[nxt]/xbuf[nxt] published
        cur = nxt;
    }

    if (half == 0) {
        out[(size_t)T_STEPS * BATCH * HID + (size_t)b * HID + j] = hj;
    }
}

extern "C" void kernel_launch(void* const* d_in, const int* in_sizes, int n_in,
                              void* d_out, int out_size, void* d_ws, size_t ws_size,
                              hipStream_t stream) {
    const float* x      = (const float*)d_in[0];
    const float* hidden = (const float*)d_in[1];
    const float* noise  = (const float*)d_in[2];
    const float* W_in   = (const float*)d_in[3];
    const float* b_in   = (const float*)d_in[4];
    const float* W_hh   = (const float*)d_in[5];
    const float* b_hh   = (const float*)d_in[6];
    float* out = (float*)d_out;

    hipLaunchKernelGGL(ctrnn_kernel, dim3(BATCH), dim3(512), 0, stream,
                       x, hidden, noise, W_in, b_in, W_hh, b_hh, out);
}